// Round 2
// baseline (142.224 us; speedup 1.0000x reference)
//
#include <hip/hip_runtime.h>
#include <stdint.h>

// Problem constants (fixed by reference setup_inputs)
#define N_NODES 8192
#define F_IN    256
#define F_OUT   64
#define N_EDGES 262144
#define LEAKY   0.2f
#define BN_EPSF 1e-5f
#define WPR     256            // bitmap words per row = N_NODES/32
#define MAXDEG  1024           // Poisson(32) -> P(deg>1024) ~ 0

typedef unsigned int u32;

__device__ __forceinline__ float lrelu(float x) {
    // slope in (0,1) -> LR(x) = max(x, slope*x); monotone increasing
    return fmaxf(x, LEAKY * x);
}

// K1: hp = h @ W (8192x256 @ 256x64), f1 = hp@a1, f2 = hp@a2.
// 4 rows per block (1 wave per row), W staged in LDS (64KB fp32).
__global__ __launch_bounds__(256) void k_hp(
    const float* __restrict__ h, const float* __restrict__ W, const float* __restrict__ a,
    float* __restrict__ hp, float* __restrict__ f1, float* __restrict__ f2)
{
    __shared__ float Wl[F_IN * F_OUT];   // 64 KB
    __shared__ float hl[4 * F_IN];       // 4 KB
    const int tid = threadIdx.x;
    for (int i = tid; i < F_IN * F_OUT; i += 256) Wl[i] = W[i];

    const int row0 = blockIdx.x * 4;
    // stage 4 rows of h: 1024 floats = 256 x float4
    const float4* h4 = reinterpret_cast<const float4*>(h + (size_t)row0 * F_IN);
    const float4 hv = h4[tid];
    hl[tid * 4 + 0] = hv.x;
    hl[tid * 4 + 1] = hv.y;
    hl[tid * 4 + 2] = hv.z;
    hl[tid * 4 + 3] = hv.w;
    __syncthreads();

    const int rl = tid >> 6, o = tid & 63;
    const float* hrow = &hl[rl * F_IN];
    float acc = 0.f;
#pragma unroll 8
    for (int k = 0; k < F_IN; ++k)
        acc += hrow[k] * Wl[k * F_OUT + o];   // bank = o&31: 2-way, free

    const int row = row0 + rl;
    hp[row * F_OUT + o] = acc;

    float p1 = acc * a[o];
    float p2 = acc * a[F_OUT + o];
#pragma unroll
    for (int off = 32; off; off >>= 1) {
        p1 += __shfl_xor(p1, off, 64);
        p2 += __shfl_xor(p2, off, 64);
    }
    if (o == 0) { f1[row] = p1; f2[row] = p2; }
}

// K2: adjacency bitmap (dedups duplicate edges, same as boolean adj in ref)
__global__ __launch_bounds__(256) void k_adj(const int* __restrict__ ei, u32* __restrict__ bm)
{
    const int e = blockIdx.x * 256 + threadIdx.x;
    const int r = ei[e];
    const int c = ei[N_EDGES + e];
    atomicOr(&bm[(size_t)r * WPR + (c >> 5)], 1u << (c & 31));
}

// K3: per-row (1 wave/row): neighbor compaction from bitmap, row max,
// softmax denom, and out_raw[i][:] = sum_j att_ij * hp[j][:]
__global__ __launch_bounds__(256) void k_attn(
    const u32* __restrict__ bm, const float* __restrict__ hp,
    const float* __restrict__ f1g, const float* __restrict__ f2g,
    float* __restrict__ Mg, float* __restrict__ Dg, float* __restrict__ outr)
{
    __shared__ int   nbr[4][MAXDEG];   // 16 KB
    __shared__ float fv [4][MAXDEG];   // 16 KB
    __shared__ int   cnt[4];
    const int tid = threadIdx.x;
    const int w = tid >> 6, lane = tid & 63;
    const int row = blockIdx.x * 4 + w;
    if (lane == 0) cnt[w] = 0;
    __syncthreads();

    float mymax = -1e30f;
    const u32* bmrow = bm + (size_t)row * WPR;
#pragma unroll
    for (int r4 = 0; r4 < 4; ++r4) {
        const int widx = r4 * 64 + lane;
        u32 bits = bmrow[widx];
        if (bits) {
            int pc = __popc(bits);
            int pos = atomicAdd(&cnt[w], pc);
            while (bits) {
                const int b = __ffs(bits) - 1;
                bits &= bits - 1;
                const int j = widx * 32 + b;
                const float v = f2g[j];
                mymax = fmaxf(mymax, v);
                if (pos < MAXDEG) { nbr[w][pos] = j; fv[w][pos] = v; }
                ++pos;
            }
        }
    }
#pragma unroll
    for (int off = 32; off; off >>= 1)
        mymax = fmaxf(mymax, __shfl_xor(mymax, off, 64));
    __syncthreads();

    const int deg = min(cnt[w], MAXDEG);
    const float f1i = f1g[row];
    float M = lrelu(f1i + mymax);
    float den = 0.f, acc = 0.f;
    for (int n = 0; n < deg; ++n) {
        const int j = nbr[w][n];              // LDS broadcast
        const float wgt = __expf(lrelu(f1i + fv[w][n]) - M);
        den += wgt;
        acc += wgt * hp[j * F_OUT + lane];    // coalesced 256B gather per wave
    }
    if (deg == 0) { den = 1.f; M = 0.f; acc = 0.f; }  // degenerate guard (P ~ e^-32)
    outr[row * F_OUT + lane] = acc / den;
    if (lane == 0) { Mg[row] = M; Dg[row] = den; }
}

// K4: per-feature mean / rstd over 8192 rows (one block per feature)
__global__ __launch_bounds__(256) void k_bnstats(
    const float* __restrict__ outr, float* __restrict__ meang, float* __restrict__ rstdg)
{
    __shared__ float ss[256], ss2[256];
    const int o = blockIdx.x, tid = threadIdx.x;
    float s = 0.f, s2 = 0.f;
    for (int i = tid; i < N_NODES; i += 256) {
        const float v = outr[i * F_OUT + o];
        s += v; s2 += v * v;
    }
    ss[tid] = s; ss2[tid] = s2;
    __syncthreads();
    for (int st = 128; st; st >>= 1) {
        if (tid < st) { ss[tid] += ss[tid + st]; ss2[tid] += ss2[tid + st]; }
        __syncthreads();
    }
    if (tid == 0) {
        const float mean = ss[0] * (1.f / N_NODES);
        const float var = ss2[0] * (1.f / N_NODES) - mean * mean;
        meang[o] = mean;
        rstdg[o] = rsqrtf(var + BN_EPSF);
    }
}

// K5: batchnorm apply + bias, fp32 out
__global__ __launch_bounds__(256) void k_bnapply(
    const float* __restrict__ outr, const float* __restrict__ meang,
    const float* __restrict__ rstdg, const float* __restrict__ gamma,
    const float* __restrict__ beta, const float* __restrict__ bias,
    float* __restrict__ out)
{
    const int idx = blockIdx.x * 256 + threadIdx.x;
    const int o = idx & 63;
    out[idx] = (outr[idx] - meang[o]) * rstdg[o] * gamma[o] + beta[o] + bias[o];
}

// K6: alpha[e] = att[row[e], col[e]]
__global__ __launch_bounds__(256) void k_alpha(
    const int* __restrict__ ei, const float* __restrict__ f1g,
    const float* __restrict__ f2g, const float* __restrict__ Mg,
    const float* __restrict__ Dg, float* __restrict__ out)
{
    const int e = blockIdx.x * 256 + threadIdx.x;
    const int r = ei[e];
    const int c = ei[N_EDGES + e];
    out[N_NODES * F_OUT + e] = __expf(lrelu(f1g[r] + f2g[c]) - Mg[r]) / Dg[r];
}

extern "C" void kernel_launch(void* const* d_in, const int* in_sizes, int n_in,
                              void* d_out, int out_size, void* d_ws, size_t ws_size,
                              hipStream_t stream) {
    const float* h     = (const float*)d_in[0];
    const int*   ei    = (const int*)  d_in[1];
    const float* W     = (const float*)d_in[2];
    const float* a     = (const float*)d_in[3];
    const float* bias  = (const float*)d_in[4];
    const float* gamma = (const float*)d_in[5];
    const float* beta  = (const float*)d_in[6];
    float* out = (float*)d_out;

    char* ws = (char*)d_ws;
    float* hp    = (float*)(ws + 0);          // 2 MB
    float* f1    = (float*)(ws + 2097152);    // 32 KB
    float* f2    = (float*)(ws + 2129920);    // 32 KB
    float* Mg    = (float*)(ws + 2162688);    // 32 KB
    float* Dg    = (float*)(ws + 2195456);    // 32 KB
    float* outr  = (float*)(ws + 2228224);    // 2 MB
    float* meang = (float*)(ws + 4325376);    // 256 B
    float* rstdg = (float*)(ws + 4325632);    // 256 B
    u32*   bm    = (u32*)  (ws + 4325888);    // 8 MB
    if (ws_size < (size_t)4325888 + (size_t)N_NODES * WPR * 4) return;

    hipMemsetAsync(bm, 0, (size_t)N_NODES * WPR * 4, stream);
    k_hp     <<<N_NODES / 4, 256, 0, stream>>>(h, W, a, hp, f1, f2);
    k_adj    <<<N_EDGES / 256, 256, 0, stream>>>(ei, bm);
    k_attn   <<<N_NODES / 4, 256, 0, stream>>>(bm, hp, f1, f2, Mg, Dg, outr);
    k_bnstats<<<F_OUT, 256, 0, stream>>>(outr, meang, rstdg);
    k_bnapply<<<(N_NODES * F_OUT) / 256, 256, 0, stream>>>(outr, meang, rstdg, gamma, beta, bias, out);
    k_alpha  <<<N_EDGES / 256, 256, 0, stream>>>(ei, f1, f2, Mg, Dg, out);
}